// Round 11
// baseline (294.788 us; speedup 1.0000x reference)
//
#include <hip/hip_runtime.h>
#include <math.h>

#define N_TOK 16384
#define HDIM  2048
#define NEXP  64
#define TOPK  8
#define NKS   4             // K split factor
#define KSEG  (HDIM / NKS)  // 512 k per block

// d_ws layout:
//   [0, 32 MiB)   : part  — partial logits f64 [NKS][N_TOK][64]
//   [33 MiB, ...) : stats — f32 probsum[64], counts[64], then int flag
#define PART_OFF  0
#define STATS_OFF (33u << 20)

typedef double d4 __attribute__((ext_vector_type(4)));

// 16-hypothesis MFMA layout probe (1 wave), exact integer arithmetic.
// flag = 1 + ai*8 + bi*4 + sf*2 + tr, or 0 if none match. (R9/R10: matched.)
__global__ void mfma_probe_kernel(int* __restrict__ flag) {
    const int l = threadIdx.x;
    const int i16 = l & 15, q = l >> 4;
    const int r4 = l >> 2,  m4 = l & 3;
    int fv = 0;
#pragma unroll
    for (int ai = 0; ai < 2; ++ai)
#pragma unroll
    for (int bi = 0; bi < 2; ++bi) {
        const int ra = ai ? r4 : i16, ka = ai ? m4 : q;
        const int cb = bi ? r4 : i16, kb = bi ? m4 : q;
        double a = (double)(ra * 4 + ka + 1);            // A[ra][ka]
        double b = (double)((kb + 1) * 100 + 3 * cb);    // B[kb][cb]
        d4 acc = {0., 0., 0., 0.};
        acc = __builtin_amdgcn_mfma_f64_16x16x4f64(a, b, acc, 0, 0, 0);
#pragma unroll
        for (int sf = 0; sf < 2; ++sf)
#pragma unroll
        for (int tr = 0; tr < 2; ++tr) {
            int ok = 1;
#pragma unroll
            for (int r = 0; r < 4; ++r) {
                const int p   = sf ? (q + 4 * r) : (4 * q + r);
                const int row = tr ? i16 : p;
                const int col = tr ? p : i16;
                double ref = 0.0;
#pragma unroll
                for (int k = 0; k < 4; ++k)
                    ref += (double)(row * 4 + k + 1) * (double)((k + 1) * 100 + 3 * col);
                ok &= (acc[r] == ref);
            }
            if (__all(ok) && fv == 0) fv = 1 + ai * 8 + bi * 4 + sf * 2 + tr;
        }
    }
    if (l == 0) *flag = fv;
}

// LDS-FREE direct-feed MFMA f64 GEMM. One f64 MFMA = 64 pipe-cycles but only
// 4 operand-dwords/lane per 4-MFMA group -> per-lane L1/L2-cached global
// loads feed it with no staging, no barriers, no bank conflicts. Feeds and
// epilogue are flag-parameterized (probe-verified mapping). Block 256 = 4
// waves (2x2): wave (wr,wc) -> 32 tok x 32 exp. Grid 1024 (256 tt x 4 ks).
// X rows: 16B/row segments, full 64B lines consumed across 4 consecutive kq
// (L1-resident). W segment 128 KB/block, L2-resident (512 KB total).
__global__ __launch_bounds__(256) void gemm_mfma_kernel(const float* __restrict__ X,
                                                        const float* __restrict__ W,
                                                        const int* __restrict__ flag,
                                                        double* __restrict__ part) {
    const int f = *flag;
    if (f == 0) return;                              // layout unresolved -> VALU path
    const int fb = f - 1;
    const int ai = (fb >> 3) & 1, bi = (fb >> 2) & 1;
    const int sf = (fb >> 1) & 1, tr = fb & 1;

    const int tt  = blockIdx.x >> 2;
    const int ks  = blockIdx.x & 3;
    const int tid = threadIdx.x;
    const int l   = tid & 63;
    const int wv  = tid >> 6;
    const int wr  = wv >> 1, wc = wv & 1;
    const int tok0 = tt * 64;
    const int k0   = ks * KSEG;

    const int i16 = l & 15, q = l >> 4, r4 = l >> 2, m4 = l & 3;
    const int ra = ai ? r4 : i16, ka = ai ? m4 : q;  // A element this lane feeds
    const int cb = bi ? r4 : i16, kb = bi ? m4 : q;  // B element this lane feeds

    // fixed per-lane operand bases; k advances 4 floats (16 B) per kq step
    const float* xa0 = X + (size_t)(tok0 + wr * 32 + ra) * HDIM + k0 + ka;
    const float* xa1 = xa0 + (size_t)16 * HDIM;
    const float* wb0 = W + (size_t)(wc * 32 + cb) * HDIM + k0 + kb;
    const float* wb1 = wb0 + (size_t)16 * HDIM;

    d4 acc00 = {0., 0., 0., 0.};
    d4 acc01 = {0., 0., 0., 0.};
    d4 acc10 = {0., 0., 0., 0.};
    d4 acc11 = {0., 0., 0., 0.};

#pragma unroll 8
    for (int kq = 0; kq < KSEG / 4; ++kq) {          // 128 K=4 steps
        float fa0 = xa0[4 * kq];
        float fa1 = xa1[4 * kq];
        float fb0 = wb0[4 * kq];
        float fb1 = wb1[4 * kq];
        double a0 = (double)fa0, a1 = (double)fa1;
        double b0 = (double)fb0, b1 = (double)fb1;
        acc00 = __builtin_amdgcn_mfma_f64_16x16x4f64(a0, b0, acc00, 0, 0, 0);
        acc01 = __builtin_amdgcn_mfma_f64_16x16x4f64(a0, b1, acc01, 0, 0, 0);
        acc10 = __builtin_amdgcn_mfma_f64_16x16x4f64(a1, b0, acc10, 0, 0, 0);
        acc11 = __builtin_amdgcn_mfma_f64_16x16x4f64(a1, b1, acc11, 0, 0, 0);
    }

    double* pbase = part + (size_t)ks * N_TOK * NEXP;
#pragma unroll
    for (int rt = 0; rt < 2; ++rt)
#pragma unroll
        for (int ct = 0; ct < 2; ++ct) {
            const d4 accv = rt == 0 ? (ct == 0 ? acc00 : acc01)
                                    : (ct == 0 ? acc10 : acc11);
#pragma unroll
            for (int r = 0; r < 4; ++r) {
                const int p    = sf ? (q + 4 * r) : (4 * q + r);
                const int dtok = tr ? i16 : p;
                const int dex  = tr ? p : i16;
                const int tok  = tok0 + wr * 32 + rt * 16 + dtok;
                const int ex   = wc * 32 + ct * 16 + dex;
                pbase[(size_t)tok * NEXP + ex] = accv[r];
            }
        }
}

// VALU fallback (R7 structure, proven math). Runs only if flag == 0.
// W staged from raw f32 W[e][k] (transpose during staging).
__global__ __launch_bounds__(512, 4) void gemm_valu_kernel(const float* __restrict__ X,
                                                           const float* __restrict__ W,
                                                           const int* __restrict__ flag,
                                                           double* __restrict__ part) {
    if (*flag != 0) return;                          // MFMA path verified -> skip
    const int tt   = blockIdx.x >> 2;
    const int ks   = blockIdx.x & 3;
    const int tid  = threadIdx.x;
    const int lane = tid & 63;                       // expert
    const int wv   = tid >> 6;                       // 0..7
    const int tok0 = tt * 64;
    const int k0   = ks * KSEG;

    __shared__ double xs[64][18];
    __shared__ double wsh[16][66];

    double acc[8];
#pragma unroll
    for (int t = 0; t < 8; ++t) acc[t] = 0.0;

    const int sx_tok = tid >> 3;
    const int sx_k   = (tid & 7) * 2;
    const float* xg  = X + (size_t)(tok0 + sx_tok) * HDIM + k0 + sx_k;
    const int sw_k = tid >> 5;                       // 0..15
    const int sw_e = (tid & 31) * 2;                 // 0..62
    const float* wg0 = W + (size_t)sw_e * HDIM + k0 + sw_k;
    const float* wg1 = W + (size_t)(sw_e + 1) * HDIM + k0 + sw_k;

    float2 px = *(const float2*)xg;
    float  pa = *wg0, pb2 = *wg1;

    for (int c = 0; c < KSEG / 16; ++c) {
        __syncthreads();
        {
            double2 xv; xv.x = (double)px.x; xv.y = (double)px.y;
            *(double2*)&xs[sx_tok][sx_k] = xv;
            double2 wv2; wv2.x = (double)pa; wv2.y = (double)pb2;
            *(double2*)&wsh[sw_k][sw_e] = wv2;
        }
        __syncthreads();
        if (c + 1 < KSEG / 16) {
            px  = *(const float2*)(xg + (c + 1) * 16);
            pa  = wg0[(c + 1) * 16];
            pb2 = wg1[(c + 1) * 16];
        }
        double wr_[16];
#pragma unroll
        for (int j = 0; j < 16; ++j) wr_[j] = wsh[j][lane];
#pragma unroll
        for (int t = 0; t < 8; ++t) {
            const int trr = wv * 8 + t;
#pragma unroll
            for (int kp = 0; kp < 8; ++kp) {
                double2 xv = *(const double2*)&xs[trr][kp * 2];
                acc[t] = fma(xv.x, wr_[kp * 2],     acc[t]);
                acc[t] = fma(xv.y, wr_[kp * 2 + 1], acc[t]);
            }
        }
    }

    double* pb = part + ((size_t)ks * N_TOK + tok0 + wv * 8) * NEXP + lane;
#pragma unroll
    for (int t = 0; t < 8; ++t)
        pb[(size_t)t * NEXP] = acc[t];
}

// Top-k (proven): coalesced stage -> f32-score argmax ladder, ties -> min idx.
__global__ __launch_bounds__(256) void topk_kernel(const double* __restrict__ part,
                                                   float* __restrict__ outIdx,
                                                   float* __restrict__ outW,
                                                   float* __restrict__ stats) {
    __shared__ float sc_s[32][65];
    __shared__ float lds_counts[NEXP];
    __shared__ float psum_part[4][NEXP];
    const int tid  = threadIdx.x;
    const int lane = tid & 63;
    const int w    = tid >> 6;
    if (tid < NEXP) lds_counts[tid] = 0.f;

    const int t0 = blockIdx.x * 32;
#pragma unroll
    for (int p = 0; p < 8; ++p) {
        const int idx = p * 256 + tid;
        const int t   = idx >> 6;
        const int e   = idx & 63;
        const double* pp = part + ((size_t)(t0 + t)) * NEXP + e;
        double l = (pp[0] + pp[(size_t)N_TOK * NEXP]) +
                   (pp[2 * (size_t)N_TOK * NEXP] + pp[3 * (size_t)N_TOK * NEXP]);
        sc_s[t][e] = (float)(1.0 / (1.0 + exp(-l)));
    }
    __syncthreads();

    float ps = 0.f;
    for (int i = 0; i < 8; ++i) {
        const int tloc = w * 8 + i;
        const int t    = t0 + tloc;
        float s = sc_s[tloc][lane];

        float rs = s;
#pragma unroll
        for (int off = 32; off; off >>= 1) rs += __shfl_xor(rs, off);
        ps += s / (rs + 1e-9f);

        float cur = s;
        float denom = 0.f;
        int   wi = 0;
        float wvv = 0.f;
#pragma unroll
        for (int k = 0; k < TOPK; ++k) {
            float m = cur; int mi = lane;
#pragma unroll
            for (int off = 32; off; off >>= 1) {
                float om = __shfl_xor(m, off);
                int   oi = __shfl_xor(mi, off);
                if (om > m || (om == m && oi < mi)) { m = om; mi = oi; }
            }
            denom += m;
            if (lane == k)  { wi = mi; wvv = m; }
            if (lane == mi) cur = -1e30f;
        }
        if (lane < TOPK) {
            outIdx[(size_t)t * TOPK + lane] = (float)wi;
            outW  [(size_t)t * TOPK + lane] = wvv / (denom + 1e-9f);
            atomicAdd(&lds_counts[wi], 1.f);
        }
    }
    psum_part[w][lane] = ps;
    __syncthreads();
    if (tid < NEXP) {
        float tot = psum_part[0][tid] + psum_part[1][tid] +
                    psum_part[2][tid] + psum_part[3][tid];
        atomicAdd(&stats[tid], tot);
        atomicAdd(&stats[NEXP + tid], lds_counts[tid]);
    }
}

__global__ void aux_kernel(const float* __restrict__ stats, float* __restrict__ out) {
    const int e = threadIdx.x;
    float prob = stats[e] / (float)N_TOK;
    float cnt  = stats[NEXP + e];
    float loadf = cnt / ((float)N_TOK * TOPK);
    float S = prob;
#pragma unroll
    for (int off = 32; off; off >>= 1) S += __shfl_xor(S, off);
    float pn = prob / (S + 1e-9f);
    float v  = loadf * pn;
#pragma unroll
    for (int off = 32; off; off >>= 1) v += __shfl_xor(v, off);
    if (e == 0) out[2 * N_TOK * TOPK] = 0.001f * v * (float)NEXP;
}

extern "C" void kernel_launch(void* const* d_in, const int* in_sizes, int n_in,
                              void* d_out, int out_size, void* d_ws, size_t ws_size,
                              hipStream_t stream) {
    (void)in_sizes; (void)n_in; (void)out_size; (void)ws_size;
    const float* X = (const float*)d_in[0];
    const float* W = (const float*)d_in[1];
    float* out = (float*)d_out;
    char*  ws  = (char*)d_ws;
    double* part  = (double*)(ws + PART_OFF);
    float*  stats = (float*)(ws + STATS_OFF);
    int*    flag  = (int*)(stats + 128);

    hipMemsetAsync(stats, 0, 132 * sizeof(float), stream);
    mfma_probe_kernel<<<1, 64, 0, stream>>>(flag);
    gemm_mfma_kernel<<<1024, 256, 0, stream>>>(X, W, flag, part);
    gemm_valu_kernel<<<1024, 512, 0, stream>>>(X, W, flag, part);
    topk_kernel<<<512, 256, 0, stream>>>(part, out, out + N_TOK * TOPK, stats);
    aux_kernel<<<1, 64, 0, stream>>>(stats, out);
}

// Round 12
// 140.723 us; speedup vs baseline: 2.0948x; 2.0948x over previous
//
#include <hip/hip_runtime.h>
#include <math.h>

#define N_TOK 16384
#define HDIM  2048
#define NEXP  64
#define TOPK  8
#define NKS   4             // K split factor
#define KSEG  (HDIM / NKS)  // 512 k per block
#define KCH   32            // k per LDS chunk
#define NCH   (KSEG / KCH)  // 16

// d_ws layout:
//   [0, 32 MiB)   : part  — partial logits f64 [NKS][N_TOK][64]
//   [33 MiB, ...) : stats — f32 probsum[64], counts[64], then int flag
#define PART_OFF  0
#define STATS_OFF (33u << 20)

typedef double d4 __attribute__((ext_vector_type(4)));

// 16-hypothesis MFMA layout probe (1 wave), exact integer arithmetic.
// flag = 1 + ai*8 + bi*4 + sf*2 + tr, or 0 if none match. (R9/R10: matched.)
__global__ void mfma_probe_kernel(int* __restrict__ flag) {
    const int l = threadIdx.x;
    const int i16 = l & 15, q = l >> 4;
    const int r4 = l >> 2,  m4 = l & 3;
    int fv = 0;
#pragma unroll
    for (int ai = 0; ai < 2; ++ai)
#pragma unroll
    for (int bi = 0; bi < 2; ++bi) {
        const int ra = ai ? r4 : i16, ka = ai ? m4 : q;
        const int cb = bi ? r4 : i16, kb = bi ? m4 : q;
        double a = (double)(ra * 4 + ka + 1);            // A[ra][ka]
        double b = (double)((kb + 1) * 100 + 3 * cb);    // B[kb][cb]
        d4 acc = {0., 0., 0., 0.};
        acc = __builtin_amdgcn_mfma_f64_16x16x4f64(a, b, acc, 0, 0, 0);
#pragma unroll
        for (int sf = 0; sf < 2; ++sf)
#pragma unroll
        for (int tr = 0; tr < 2; ++tr) {
            int ok = 1;
#pragma unroll
            for (int r = 0; r < 4; ++r) {
                const int p   = sf ? (q + 4 * r) : (4 * q + r);
                const int row = tr ? i16 : p;
                const int col = tr ? p : i16;
                double ref = 0.0;
#pragma unroll
                for (int k = 0; k < 4; ++k)
                    ref += (double)(row * 4 + k + 1) * (double)((k + 1) * 100 + 3 * col);
                ok &= (acc[r] == ref);
            }
            if (__all(ok) && fv == 0) fv = 1 + ai * 8 + bi * 4 + sf * 2 + tr;
        }
    }
    if (l == 0) *flag = fv;
}

// MFMA f64 GEMM, R9 proven structure widened to 8 waves/block for TLP.
// Block 512 thr = 8 waves in 2(tok)x4(exp): wave (wr,wc) -> 32 tok x 16 exp
// (2 accs). Tile 64 tok x 64 exp x 512 k; grid 1024 (256 tt x 4 ks).
// 4 blocks/CU x 8 waves = 32 waves/CU (8/SIMD) so MFMA issue continues
// through barrier/stage windows. launch_bounds(512,8) caps VGPR at 64.
__global__ __launch_bounds__(512, 8) void gemm_mfma_kernel(const float* __restrict__ X,
                                                           const float* __restrict__ W,
                                                           const int* __restrict__ flag,
                                                           double* __restrict__ part) {
    const int f = *flag;
    if (f == 0) return;                              // layout unresolved -> VALU path
    const int fb = f - 1;
    const int ai = (fb >> 3) & 1, bi = (fb >> 2) & 1;
    const int sf = (fb >> 1) & 1, tr = fb & 1;

    const int tt  = blockIdx.x >> 2;
    const int ks  = blockIdx.x & 3;
    const int tid = threadIdx.x;
    const int l   = tid & 63;
    const int wv  = tid >> 6;                        // 0..7
    const int wr  = wv >> 2;                         // 0..1: 32-token group
    const int wc  = wv & 3;                          // 0..3: 16-expert group
    const int tok0 = tt * 64;
    const int k0   = ks * KSEG;

    const int i16 = l & 15, q = l >> 4, r4 = l >> 2, m4 = l & 3;
    const int ra = ai ? r4 : i16, ka = ai ? m4 : q;  // A element this lane feeds
    const int cb = bi ? r4 : i16, kb = bi ? m4 : q;  // B element this lane feeds

    __shared__ double Xs[64][34];                    // 64 tok x 32 k (+2 pad)
    __shared__ double Ws[64][34];                    // 64 exp x 32 k (+2 pad)

    d4 acc0 = {0., 0., 0., 0.};
    d4 acc1 = {0., 0., 0., 0.};

    // staging: thread -> row tid>>3 (0..63), cols 4*(tid&7)..+3 (one float4 each)
    const int sr = tid >> 3;
    const int sc = (tid & 7) * 4;
    const float* xg = X + (size_t)(tok0 + sr) * HDIM + k0 + sc;
    const float* wg = W + (size_t)sr * HDIM + k0 + sc;

    float4 px = *(const float4*)xg;
    float4 pw = *(const float4*)wg;

    for (int c = 0; c < NCH; ++c) {
        __syncthreads();                             // readers of previous chunk done
        {
            double2 d0, d1;
            d0.x = (double)px.x; d0.y = (double)px.y;
            d1.x = (double)px.z; d1.y = (double)px.w;
            *(double2*)&Xs[sr][sc]     = d0;
            *(double2*)&Xs[sr][sc + 2] = d1;
            d0.x = (double)pw.x; d0.y = (double)pw.y;
            d1.x = (double)pw.z; d1.y = (double)pw.w;
            *(double2*)&Ws[sr][sc]     = d0;
            *(double2*)&Ws[sr][sc + 2] = d1;
        }
        __syncthreads();
        if (c + 1 < NCH) {                           // prefetch next chunk into regs
            px = *(const float4*)(xg + (c + 1) * KCH);
            pw = *(const float4*)(wg + (c + 1) * KCH);
        }
        const double* pa0 = &Xs[wr * 32 + ra][ka];
        const double* pa1 = &Xs[wr * 32 + 16 + ra][ka];
        const double* pb0 = &Ws[wc * 16 + cb][kb];
#pragma unroll
        for (int kq = 0; kq < 8; ++kq) {             // 8 K=4 steps: 3 b64 reads, 2 MFMAs
            double a0 = pa0[4 * kq];
            double a1 = pa1[4 * kq];
            double b0 = pb0[4 * kq];
            acc0 = __builtin_amdgcn_mfma_f64_16x16x4f64(a0, b0, acc0, 0, 0, 0);
            acc1 = __builtin_amdgcn_mfma_f64_16x16x4f64(a1, b0, acc1, 0, 0, 0);
        }
    }

    double* pbase = part + (size_t)ks * N_TOK * NEXP;
#pragma unroll
    for (int rt = 0; rt < 2; ++rt) {
        const d4 accv = rt == 0 ? acc0 : acc1;
#pragma unroll
        for (int r = 0; r < 4; ++r) {
            const int p    = sf ? (q + 4 * r) : (4 * q + r);
            const int dtok = tr ? i16 : p;
            const int dex  = tr ? p : i16;
            const int tok  = tok0 + wr * 32 + rt * 16 + dtok;
            const int ex   = wc * 16 + dex;
            pbase[(size_t)tok * NEXP + ex] = accv[r];
        }
    }
}

// VALU fallback (R7 structure, proven math). Runs only if flag == 0.
// W staged from raw f32 W[e][k] (transpose during staging).
__global__ __launch_bounds__(512, 4) void gemm_valu_kernel(const float* __restrict__ X,
                                                           const float* __restrict__ W,
                                                           const int* __restrict__ flag,
                                                           double* __restrict__ part) {
    if (*flag != 0) return;                          // MFMA path verified -> skip
    const int tt   = blockIdx.x >> 2;
    const int ks   = blockIdx.x & 3;
    const int tid  = threadIdx.x;
    const int lane = tid & 63;                       // expert
    const int wv   = tid >> 6;                       // 0..7
    const int tok0 = tt * 64;
    const int k0   = ks * KSEG;

    __shared__ double xs[64][18];
    __shared__ double wsh[16][66];

    double acc[8];
#pragma unroll
    for (int t = 0; t < 8; ++t) acc[t] = 0.0;

    const int sx_tok = tid >> 3;
    const int sx_k   = (tid & 7) * 2;
    const float* xg  = X + (size_t)(tok0 + sx_tok) * HDIM + k0 + sx_k;
    const int sw_k = tid >> 5;                       // 0..15
    const int sw_e = (tid & 31) * 2;                 // 0..62
    const float* wg0 = W + (size_t)sw_e * HDIM + k0 + sw_k;
    const float* wg1 = W + (size_t)(sw_e + 1) * HDIM + k0 + sw_k;

    float2 px = *(const float2*)xg;
    float  pa = *wg0, pb2 = *wg1;

    for (int c = 0; c < KSEG / 16; ++c) {
        __syncthreads();
        {
            double2 xv; xv.x = (double)px.x; xv.y = (double)px.y;
            *(double2*)&xs[sx_tok][sx_k] = xv;
            double2 wv2; wv2.x = (double)pa; wv2.y = (double)pb2;
            *(double2*)&wsh[sw_k][sw_e] = wv2;
        }
        __syncthreads();
        if (c + 1 < KSEG / 16) {
            px  = *(const float2*)(xg + (c + 1) * 16);
            pa  = wg0[(c + 1) * 16];
            pb2 = wg1[(c + 1) * 16];
        }
        double wr_[16];
#pragma unroll
        for (int j = 0; j < 16; ++j) wr_[j] = wsh[j][lane];
#pragma unroll
        for (int t = 0; t < 8; ++t) {
            const int trr = wv * 8 + t;
#pragma unroll
            for (int kp = 0; kp < 8; ++kp) {
                double2 xv = *(const double2*)&xs[trr][kp * 2];
                acc[t] = fma(xv.x, wr_[kp * 2],     acc[t]);
                acc[t] = fma(xv.y, wr_[kp * 2 + 1], acc[t]);
            }
        }
    }

    double* pb = part + ((size_t)ks * N_TOK + tok0 + wv * 8) * NEXP + lane;
#pragma unroll
    for (int t = 0; t < 8; ++t)
        pb[(size_t)t * NEXP] = acc[t];
}

// Top-k (proven): coalesced stage -> f32-score argmax ladder, ties -> min idx.
__global__ __launch_bounds__(256) void topk_kernel(const double* __restrict__ part,
                                                   float* __restrict__ outIdx,
                                                   float* __restrict__ outW,
                                                   float* __restrict__ stats) {
    __shared__ float sc_s[32][65];
    __shared__ float lds_counts[NEXP];
    __shared__ float psum_part[4][NEXP];
    const int tid  = threadIdx.x;
    const int lane = tid & 63;
    const int w    = tid >> 6;
    if (tid < NEXP) lds_counts[tid] = 0.f;

    const int t0 = blockIdx.x * 32;
#pragma unroll
    for (int p = 0; p < 8; ++p) {
        const int idx = p * 256 + tid;
        const int t   = idx >> 6;
        const int e   = idx & 63;
        const double* pp = part + ((size_t)(t0 + t)) * NEXP + e;
        double l = (pp[0] + pp[(size_t)N_TOK * NEXP]) +
                   (pp[2 * (size_t)N_TOK * NEXP] + pp[3 * (size_t)N_TOK * NEXP]);
        sc_s[t][e] = (float)(1.0 / (1.0 + exp(-l)));
    }
    __syncthreads();

    float ps = 0.f;
    for (int i = 0; i < 8; ++i) {
        const int tloc = w * 8 + i;
        const int t    = t0 + tloc;
        float s = sc_s[tloc][lane];

        float rs = s;
#pragma unroll
        for (int off = 32; off; off >>= 1) rs += __shfl_xor(rs, off);
        ps += s / (rs + 1e-9f);

        float cur = s;
        float denom = 0.f;
        int   wi = 0;
        float wvv = 0.f;
#pragma unroll
        for (int k = 0; k < TOPK; ++k) {
            float m = cur; int mi = lane;
#pragma unroll
            for (int off = 32; off; off >>= 1) {
                float om = __shfl_xor(m, off);
                int   oi = __shfl_xor(mi, off);
                if (om > m || (om == m && oi < mi)) { m = om; mi = oi; }
            }
            denom += m;
            if (lane == k)  { wi = mi; wvv = m; }
            if (lane == mi) cur = -1e30f;
        }
        if (lane < TOPK) {
            outIdx[(size_t)t * TOPK + lane] = (float)wi;
            outW  [(size_t)t * TOPK + lane] = wvv / (denom + 1e-9f);
            atomicAdd(&lds_counts[wi], 1.f);
        }
    }
    psum_part[w][lane] = ps;
    __syncthreads();
    if (tid < NEXP) {
        float tot = psum_part[0][tid] + psum_part[1][tid] +
                    psum_part[2][tid] + psum_part[3][tid];
        atomicAdd(&stats[tid], tot);
        atomicAdd(&stats[NEXP + tid], lds_counts[tid]);
    }
}

__global__ void aux_kernel(const float* __restrict__ stats, float* __restrict__ out) {
    const int e = threadIdx.x;
    float prob = stats[e] / (float)N_TOK;
    float cnt  = stats[NEXP + e];
    float loadf = cnt / ((float)N_TOK * TOPK);
    float S = prob;
#pragma unroll
    for (int off = 32; off; off >>= 1) S += __shfl_xor(S, off);
    float pn = prob / (S + 1e-9f);
    float v  = loadf * pn;
#pragma unroll
    for (int off = 32; off; off >>= 1) v += __shfl_xor(v, off);
    if (e == 0) out[2 * N_TOK * TOPK] = 0.001f * v * (float)NEXP;
}

extern "C" void kernel_launch(void* const* d_in, const int* in_sizes, int n_in,
                              void* d_out, int out_size, void* d_ws, size_t ws_size,
                              hipStream_t stream) {
    (void)in_sizes; (void)n_in; (void)out_size; (void)ws_size;
    const float* X = (const float*)d_in[0];
    const float* W = (const float*)d_in[1];
    float* out = (float*)d_out;
    char*  ws  = (char*)d_ws;
    double* part  = (double*)(ws + PART_OFF);
    float*  stats = (float*)(ws + STATS_OFF);
    int*    flag  = (int*)(stats + 128);

    hipMemsetAsync(stats, 0, 132 * sizeof(float), stream);
    mfma_probe_kernel<<<1, 64, 0, stream>>>(flag);
    gemm_mfma_kernel<<<1024, 512, 0, stream>>>(X, W, flag, part);
    gemm_valu_kernel<<<1024, 512, 0, stream>>>(X, W, flag, part);
    topk_kernel<<<512, 256, 0, stream>>>(part, out, out + N_TOK * TOPK, stats);
    aux_kernel<<<1, 64, 0, stream>>>(stats, out);
}